// Round 1
// baseline (895.734 us; speedup 1.0000x reference)
//
#include <hip/hip_runtime.h>

#define PATH_LEN 16

__global__ __launch_bounds__(256) void marble_wander_kernel(
    const float* __restrict__ x,
    const int*   __restrict__ paths,   // [n][16] int32
    const float* __restrict__ weights, // [2^21]
    float*       __restrict__ out,
    int n)
{
    int i = blockIdx.x * blockDim.x + threadIdx.x;
    if (i >= n) return;

    // 16 path indices = 64 contiguous bytes -> 4x int4 vector loads (coalesced)
    const int4* p = reinterpret_cast<const int4*>(paths) + (size_t)i * 4;
    int4 p0 = p[0];
    int4 p1 = p[1];
    int4 p2 = p[2];
    int4 p3 = p[3];

    // 16 independent scattered gathers from the 8 MB table (L2/L3-resident).
    float w0  = weights[p0.x];
    float w1  = weights[p0.y];
    float w2  = weights[p0.z];
    float w3  = weights[p0.w];
    float w4  = weights[p1.x];
    float w5  = weights[p1.y];
    float w6  = weights[p1.z];
    float w7  = weights[p1.w];
    float w8  = weights[p2.x];
    float w9  = weights[p2.y];
    float w10 = weights[p2.z];
    float w11 = weights[p2.w];
    float w12 = weights[p3.x];
    float w13 = weights[p3.y];
    float w14 = weights[p3.z];
    float w15 = weights[p3.w];

    float xv = x[i];

    // Pairwise product tree (short dependency chain; fp32 assoc. noise ~1e-6)
    float a0 = w0  * w1;
    float a1 = w2  * w3;
    float a2 = w4  * w5;
    float a3 = w6  * w7;
    float a4 = w8  * w9;
    float a5 = w10 * w11;
    float a6 = w12 * w13;
    float a7 = w14 * w15;

    float b0 = a0 * a1;
    float b1 = a2 * a3;
    float b2 = a4 * a5;
    float b3 = a6 * a7;

    float c0 = b0 * b1;
    float c1 = b2 * b3;

    out[i] = xv * (c0 * c1);
}

extern "C" void kernel_launch(void* const* d_in, const int* in_sizes, int n_in,
                              void* d_out, int out_size, void* d_ws, size_t ws_size,
                              hipStream_t stream) {
    const float* x       = (const float*)d_in[0];
    const int*   paths   = (const int*)d_in[1];
    const float* weights = (const float*)d_in[2];
    float*       out     = (float*)d_out;

    int n = in_sizes[0]; // 2048*2048 = 4194304
    int block = 256;
    int grid = (n + block - 1) / block;
    marble_wander_kernel<<<grid, block, 0, stream>>>(x, paths, weights, out, n);
}

// Round 3
// 669.240 us; speedup vs baseline: 1.3384x; 1.3384x over previous
//
#include <hip/hip_runtime.h>

typedef int v4i __attribute__((ext_vector_type(4)));

#define LOG2_CHUNK 19   // 2^19 floats = 2 MB chunk (fits per-XCD 4 MB L2 with headroom)
#define NCHUNK 4        // 2^21 / 2^19

__global__ __launch_bounds__(256) void marble_wander_kernel(
    const float* __restrict__ x,
    const int*   __restrict__ paths,   // [n][16] int32
    const float* __restrict__ weights, // [2^21] floats, 8 MB
    float*       __restrict__ out,
    int n)
{
    int i = blockIdx.x * blockDim.x + threadIdx.x;
    bool valid = (i < n);
    int ii = valid ? i : 0;

    // 16 path indices = 64 contiguous bytes -> 4x 16B vector loads, nt-hinted
    // (streamed once; don't evict the resident weight chunk from L2).
    const v4i* p = reinterpret_cast<const v4i*>(paths) + (size_t)ii * 4;
    v4i p0 = __builtin_nontemporal_load(p + 0);
    v4i p1 = __builtin_nontemporal_load(p + 1);
    v4i p2 = __builtin_nontemporal_load(p + 2);
    v4i p3 = __builtin_nontemporal_load(p + 3);

    int idx[16] = { p0.x, p0.y, p0.z, p0.w,
                    p1.x, p1.y, p1.z, p1.w,
                    p2.x, p2.y, p2.z, p2.w,
                    p3.x, p3.y, p3.z, p3.w };

    // 4 partial products for ILP (avoid one serial load->mul chain).
    float a0 = 1.0f, a1 = 1.0f, a2 = 1.0f, a3 = 1.0f;

    // Chunk-phased gather: product is commutative, so apply weights in table
    // order. All co-resident waves sweep the same 2 MB window together ->
    // gathers hit L2 instead of spilling to L3/HBM line fills.
    #pragma unroll
    for (int c = 0; c < NCHUNK; ++c) {
        #pragma unroll
        for (int j = 0; j < 16; ++j) {
            if ((((unsigned)idx[j]) >> LOG2_CHUNK) == (unsigned)c) {
                float w = weights[idx[j]];
                if      ((j & 3) == 0) a0 *= w;
                else if ((j & 3) == 1) a1 *= w;
                else if ((j & 3) == 2) a2 *= w;
                else                   a3 *= w;
            }
        }
        // Limit intra-block phase skew + fence gather hoisting across phases.
        __syncthreads();
    }

    float xv = __builtin_nontemporal_load(&x[ii]);
    float r  = xv * ((a0 * a1) * (a2 * a3));
    if (valid) __builtin_nontemporal_store(r, &out[i]);
}

extern "C" void kernel_launch(void* const* d_in, const int* in_sizes, int n_in,
                              void* d_out, int out_size, void* d_ws, size_t ws_size,
                              hipStream_t stream) {
    const float* x       = (const float*)d_in[0];
    const int*   paths   = (const int*)d_in[1];
    const float* weights = (const float*)d_in[2];
    float*       out     = (float*)d_out;

    int n = in_sizes[0]; // 2048*2048 = 4194304
    int block = 256;
    int grid = (n + block - 1) / block;
    marble_wander_kernel<<<grid, block, 0, stream>>>(x, paths, weights, out, n);
}